// Round 7
// baseline (50.303 us; speedup 1.0000x reference)
//
#include <hip/hip_runtime.h>

namespace {
constexpr int Cc   = 32;
constexpr int H    = 128;
constexpr int W    = 128;
constexpr int HWsz = H * W;        // 16384
constexpr int NPIX = 8 * HWsz;     // 131072
constexpr int NROW = NPIX / W;     // 1024 rows -> one block per row
constexpr int CPG  = 8;            // channels per group (4 groups = 4 waves)
}

__device__ inline float2 mk2(float a, float b) { float2 r; r.x = a; r.y = b; return r; }
__device__ inline void fma2(float2& acc, const float2& a, const float2& b) {
    acc.x += a.x * b.x; acc.y += a.y * b.y;
}
__device__ inline void add2(float2& acc, const float2& v) { acc.x += v.x; acc.y += v.y; }

// Fused single kernel: sim[9] + ||A|| + neighbor ||B|| + softmax-CE + grid reduce.
// 1024 row-blocks x 4 waves. All 32 loads hoisted for MLP; VGPR cap 128 via (256,4).
__global__ __launch_bounds__(256, 4) void cl_fused_kernel(const float* __restrict__ A,
                                                          const float* __restrict__ B,
                                                          double* __restrict__ partial,
                                                          unsigned* __restrict__ cnt,
                                                          float* __restrict__ out) {
    __shared__ float2 ls[13][192];   // sim[9], bn[3], sa — lane-consecutive
    __shared__ double sd[256];
    __shared__ int lastFlag;

    int t   = threadIdx.x & 63;      // lane: 2 pixels each
    int g   = threadIdx.x >> 6;      // channel group == wave id (0..3)
    int row = blockIdx.x;            // global row 0..1023
    int b   = row >> 7;
    int h   = row & (H - 1);
    int w0  = t * 2;

    int hc[3];
#pragma unroll
    for (int r = 0; r < 3; ++r) hc[r] = min(max(h + r - 1, 0), H - 1);

    const float* Ap  = A + (size_t)b * Cc * HWsz + (size_t)g * CPG * HWsz + h * W + w0;
    const float* Bg  = B + (size_t)b * Cc * HWsz + (size_t)g * CPG * HWsz;
    const float* Br0 = Bg + hc[0] * W + w0;
    const float* Br1 = Bg + hc[1] * W + w0;
    const float* Br2 = Bg + hc[2] * W + w0;

    // ---- hoist ALL loads (32 x float2 = 64 VGPRs) so they issue back-to-back ----
    float2 av[CPG], b0v[CPG], b1v[CPG], b2v[CPG];
#pragma unroll
    for (int c = 0; c < CPG; ++c) {
        av[c]  = *(const float2*)(Ap  + c * HWsz);
        b0v[c] = *(const float2*)(Br0 + c * HWsz);
        b1v[c] = *(const float2*)(Br1 + c * HWsz);
        b2v[c] = *(const float2*)(Br2 + c * HWsz);
    }

    float2 sim[9], bn[3];
#pragma unroll
    for (int k = 0; k < 9; ++k) sim[k] = mk2(0, 0);
#pragma unroll
    for (int r = 0; r < 3; ++r) bn[r] = mk2(0, 0);
    float2 sa2 = mk2(0, 0);

#pragma unroll
    for (int c = 0; c < CPG; ++c) {
        float2 a2 = av[c], b0 = b0v[c], b1 = b1v[c], b2 = b2v[c];
        float l0 = __shfl_up(b0.y, 1, 64), r0 = __shfl_down(b0.x, 1, 64);
        float l1 = __shfl_up(b1.y, 1, 64), r1 = __shfl_down(b1.x, 1, 64);
        float l2 = __shfl_up(b2.y, 1, 64), r2 = __shfl_down(b2.x, 1, 64);
        fma2(sa2, a2, a2);
        fma2(bn[0], b0, b0);
        fma2(bn[1], b1, b1);
        fma2(bn[2], b2, b2);
        fma2(sim[0], a2, mk2(l0, b0.x));
        fma2(sim[1], a2, b0);
        fma2(sim[2], a2, mk2(b0.y, r0));
        fma2(sim[3], a2, mk2(l1, b1.x));
        fma2(sim[4], a2, b1);
        fma2(sim[5], a2, mk2(b1.y, r1));
        fma2(sim[6], a2, mk2(l2, b2.x));
        fma2(sim[7], a2, b2);
        fma2(sim[8], a2, mk2(b2.y, r2));
    }

    if (g != 0) {
        int idx = (g - 1) * 64 + t;
#pragma unroll
        for (int k = 0; k < 9; ++k) ls[k][idx] = sim[k];
        ls[9][idx]  = bn[0];
        ls[10][idx] = bn[1];
        ls[11][idx] = bn[2];
        ls[12][idx] = sa2;
    }
    __syncthreads();

    if (g == 0) {
#pragma unroll
        for (int gg = 0; gg < 3; ++gg) {
            int idx = gg * 64 + t;
#pragma unroll
            for (int k = 0; k < 9; ++k) add2(sim[k], ls[k][idx]);
            add2(bn[0], ls[9][idx]);
            add2(bn[1], ls[10][idx]);
            add2(bn[2], ls[11][idx]);
            add2(sa2,   ls[12][idx]);
        }

        float2 rn[3]; float rlf[3], rrt[3];
#pragma unroll
        for (int r = 0; r < 3; ++r) {
            rn[r].x = 1.0f / fmaxf(sqrtf(bn[r].x), 1e-12f);
            rn[r].y = 1.0f / fmaxf(sqrtf(bn[r].y), 1e-12f);
            rlf[r] = __shfl_up(rn[r].y, 1, 64);
            rrt[r] = __shfl_down(rn[r].x, 1, 64);
        }

        float accf = 0.f;
#pragma unroll
        for (int j = 0; j < 2; ++j) {
            float ra = 1.0f / fmaxf(sqrtf(j == 0 ? sa2.x : sa2.y), 1e-12f);
            float lg[9], sv[9];
#pragma unroll
            for (int r = 0; r < 3; ++r) {
                bool vr_ = ((unsigned)(h + r - 1) < (unsigned)H);   // block-uniform
                float nl = (j == 0) ? rlf[r]  : rn[r].x;
                float nm = (j == 0) ? rn[r].x : rn[r].y;
                float nr = (j == 0) ? rn[r].y : rrt[r];
                bool vl  = vr_ && (j == 1 || t > 0);
                bool vrg = vr_ && (j == 0 || t < 63);
                float s0v = (j == 0) ? sim[r * 3 + 0].x : sim[r * 3 + 0].y;
                float s1v = (j == 0) ? sim[r * 3 + 1].x : sim[r * 3 + 1].y;
                float s2v = (j == 0) ? sim[r * 3 + 2].x : sim[r * 3 + 2].y;
                float s0 = vl  ? s0v * ra * nl : 0.f;
                float s1 = vr_ ? s1v * ra * nm : 0.f;
                float s2 = vrg ? s2v * ra * nr : 0.f;
                sv[r * 3 + 0] = s0; lg[r * 3 + 0] = s0 / 0.07f;
                sv[r * 3 + 1] = s1; lg[r * 3 + 1] = s1 / 0.07f;
                sv[r * 3 + 2] = s2; lg[r * 3 + 2] = s2 / 0.07f;
            }
            float m = -1e30f;
#pragma unroll
            for (int k = 0; k < 9; ++k) m = fmaxf(m, lg[k]);
            float Z = 0.f;
#pragma unroll
            for (int k = 0; k < 9; ++k) Z += expf(lg[k] - m);
            float lZ = logf(Z);
#pragma unroll
            for (int k = 0; k < 9; ++k)
                if (sv[k] > 0.5f) accf += (m + lZ - lg[k]);
        }

        double acc = (double)accf;
#pragma unroll
        for (int s = 32; s > 0; s >>= 1) acc += __shfl_down(acc, s, 64);
        if (t == 0) {
            partial[row] = acc;
            // Release (waitcnt drains the store) + count. No threadfence.
            unsigned c = __hip_atomic_fetch_add(cnt, 1u, __ATOMIC_ACQ_REL,
                                                __HIP_MEMORY_SCOPE_AGENT);
            lastFlag = (c == (unsigned)(NROW - 1)) ? 1 : 0;
        }
    }
    __syncthreads();

    if (lastFlag) {   // block-uniform
        double a2 = 0.0;
#pragma unroll
        for (int i = 0; i < 4; ++i)
            a2 += __hip_atomic_load(&partial[threadIdx.x + i * 256],
                                    __ATOMIC_RELAXED, __HIP_MEMORY_SCOPE_AGENT);
        sd[threadIdx.x] = a2;
        __syncthreads();
        for (int s = 128; s > 0; s >>= 1) {
            if (threadIdx.x < s) sd[threadIdx.x] += sd[threadIdx.x + s];
            __syncthreads();
        }
        if (threadIdx.x == 0) out[0] = (float)(sd[0] / (double)NPIX);
    }
}

extern "C" void kernel_launch(void* const* d_in, const int* in_sizes, int n_in,
                              void* d_out, int out_size, void* d_ws, size_t ws_size,
                              hipStream_t stream) {
    const float* A = (const float*)d_in[0];
    const float* B = (const float*)d_in[1];
    float* out = (float*)d_out;

    char* ws = (char*)d_ws;
    double*   partial = (double*)ws;                 // 1024 * 8 = 8 KiB
    unsigned* cnt     = (unsigned*)(ws + 8192);      // 4 B

    hipMemsetAsync(cnt, 0, sizeof(unsigned), stream);
    cl_fused_kernel<<<NROW, 256, 0, stream>>>(A, B, partial, cnt, out);
}

// Round 8
// 16.551 us; speedup vs baseline: 3.0392x; 3.0392x over previous
//
#include <hip/hip_runtime.h>

namespace {
constexpr int Cc   = 32;
constexpr int H    = 128;
constexpr int W    = 128;
constexpr int HWsz = H * W;        // 16384
constexpr int NPIX = 8 * HWsz;     // 131072
constexpr int NROW = NPIX / W;     // 1024 rows -> one block per row
constexpr int CPG  = 8;            // channels per group (4 groups = 4 waves)
}

__device__ inline float2 mk2(float a, float b) { float2 r; r.x = a; r.y = b; return r; }
__device__ inline void fma2(float2& acc, const float2& a, const float2& b) {
    acc.x += a.x * b.x; acc.y += a.y * b.y;
}
__device__ inline void add2(float2& acc, const float2& v) { acc.x += v.x; acc.y += v.y; }

// Fused: per-pixel sim[9] + ||A|| + neighbor ||B|| + softmax-CE, one row per block.
// XCD swizzle: image = blockIdx & 7 (matches round-robin XCD dispatch), so each
// XCD's 4MB L2 holds exactly one image's A+B slice (4.2MB) across replays.
__global__ __launch_bounds__(256) void cl_fused_kernel(const float* __restrict__ A,
                                                       const float* __restrict__ B,
                                                       double* __restrict__ partial) {
    __shared__ float2 ls[13][192];   // sim[9], bn[3], sa — lane-consecutive

    int t   = threadIdx.x & 63;      // lane: 2 pixels each
    int g   = threadIdx.x >> 6;      // channel group == wave id
    int blk = blockIdx.x;
    int b   = blk & 7;               // image == XCD
    int h   = blk >> 3;              // row 0..127 (consecutive rows of an image
    int w0  = t * 2;                 //  are 8 apart in blk -> same XCD)

    int hc[3];
#pragma unroll
    for (int r = 0; r < 3; ++r) hc[r] = min(max(h + r - 1, 0), H - 1);

    const float* Ap  = A + (size_t)b * Cc * HWsz + (size_t)g * CPG * HWsz + h * W + w0;
    const float* Bg  = B + (size_t)b * Cc * HWsz + (size_t)g * CPG * HWsz;
    const float* Br0 = Bg + hc[0] * W + w0;
    const float* Br1 = Bg + hc[1] * W + w0;
    const float* Br2 = Bg + hc[2] * W + w0;

    float2 sim[9], bn[3];
#pragma unroll
    for (int k = 0; k < 9; ++k) sim[k] = mk2(0, 0);
#pragma unroll
    for (int r = 0; r < 3; ++r) bn[r] = mk2(0, 0);
    float2 sa2 = mk2(0, 0);

#pragma unroll
    for (int c = 0; c < CPG; ++c) {
        float2 a2 = *(const float2*)(Ap  + c * HWsz);
        float2 b0 = *(const float2*)(Br0 + c * HWsz);
        float2 b1 = *(const float2*)(Br1 + c * HWsz);
        float2 b2 = *(const float2*)(Br2 + c * HWsz);
        float l0 = __shfl_up(b0.y, 1, 64), r0 = __shfl_down(b0.x, 1, 64);
        float l1 = __shfl_up(b1.y, 1, 64), r1 = __shfl_down(b1.x, 1, 64);
        float l2 = __shfl_up(b2.y, 1, 64), r2 = __shfl_down(b2.x, 1, 64);
        fma2(sa2, a2, a2);
        fma2(bn[0], b0, b0);
        fma2(bn[1], b1, b1);
        fma2(bn[2], b2, b2);
        fma2(sim[0], a2, mk2(l0, b0.x));
        fma2(sim[1], a2, b0);
        fma2(sim[2], a2, mk2(b0.y, r0));
        fma2(sim[3], a2, mk2(l1, b1.x));
        fma2(sim[4], a2, b1);
        fma2(sim[5], a2, mk2(b1.y, r1));
        fma2(sim[6], a2, mk2(l2, b2.x));
        fma2(sim[7], a2, b2);
        fma2(sim[8], a2, mk2(b2.y, r2));
    }

    if (g != 0) {
        int idx = (g - 1) * 64 + t;
#pragma unroll
        for (int k = 0; k < 9; ++k) ls[k][idx] = sim[k];
        ls[9][idx]  = bn[0];
        ls[10][idx] = bn[1];
        ls[11][idx] = bn[2];
        ls[12][idx] = sa2;
    }
    __syncthreads();

    if (g == 0) {
#pragma unroll
        for (int gg = 0; gg < 3; ++gg) {
            int idx = gg * 64 + t;
#pragma unroll
            for (int k = 0; k < 9; ++k) add2(sim[k], ls[k][idx]);
            add2(bn[0], ls[9][idx]);
            add2(bn[1], ls[10][idx]);
            add2(bn[2], ls[11][idx]);
            add2(sa2,   ls[12][idx]);
        }

        float2 rn[3]; float rlf[3], rrt[3];
#pragma unroll
        for (int r = 0; r < 3; ++r) {
            rn[r].x = 1.0f / fmaxf(sqrtf(bn[r].x), 1e-12f);
            rn[r].y = 1.0f / fmaxf(sqrtf(bn[r].y), 1e-12f);
            rlf[r] = __shfl_up(rn[r].y, 1, 64);
            rrt[r] = __shfl_down(rn[r].x, 1, 64);
        }

        float accf = 0.f;
#pragma unroll
        for (int j = 0; j < 2; ++j) {
            float ra = 1.0f / fmaxf(sqrtf(j == 0 ? sa2.x : sa2.y), 1e-12f);
            float lg[9], sv[9];
#pragma unroll
            for (int r = 0; r < 3; ++r) {
                bool vr_ = ((unsigned)(h + r - 1) < (unsigned)H);   // block-uniform
                float nl = (j == 0) ? rlf[r]  : rn[r].x;
                float nm = (j == 0) ? rn[r].x : rn[r].y;
                float nr = (j == 0) ? rn[r].y : rrt[r];
                bool vl  = vr_ && (j == 1 || t > 0);
                bool vrg = vr_ && (j == 0 || t < 63);
                float s0v = (j == 0) ? sim[r * 3 + 0].x : sim[r * 3 + 0].y;
                float s1v = (j == 0) ? sim[r * 3 + 1].x : sim[r * 3 + 1].y;
                float s2v = (j == 0) ? sim[r * 3 + 2].x : sim[r * 3 + 2].y;
                float s0 = vl  ? s0v * ra * nl : 0.f;
                float s1 = vr_ ? s1v * ra * nm : 0.f;
                float s2 = vrg ? s2v * ra * nr : 0.f;
                sv[r * 3 + 0] = s0; lg[r * 3 + 0] = s0 / 0.07f;
                sv[r * 3 + 1] = s1; lg[r * 3 + 1] = s1 / 0.07f;
                sv[r * 3 + 2] = s2; lg[r * 3 + 2] = s2 / 0.07f;
            }
            float m = -1e30f;
#pragma unroll
            for (int k = 0; k < 9; ++k) m = fmaxf(m, lg[k]);
            float Z = 0.f;
#pragma unroll
            for (int k = 0; k < 9; ++k) Z += expf(lg[k] - m);
            float lZ = logf(Z);
#pragma unroll
            for (int k = 0; k < 9; ++k)
                if (sv[k] > 0.5f) accf += (m + lZ - lg[k]);
        }

        double acc = (double)accf;
#pragma unroll
        for (int s = 32; s > 0; s >>= 1) acc += __shfl_down(acc, s, 64);
        if (t == 0) partial[blk] = acc;
    }
}

__global__ __launch_bounds__(256) void cl_final_kernel(const double* __restrict__ partial,
                                                       float* __restrict__ out) {
    __shared__ double sd[256];
    double acc = 0.0;
    for (int i = threadIdx.x; i < NROW; i += 256) acc += partial[i];
    sd[threadIdx.x] = acc;
    __syncthreads();
    for (int s = 128; s > 0; s >>= 1) {
        if (threadIdx.x < s) sd[threadIdx.x] += sd[threadIdx.x + s];
        __syncthreads();
    }
    if (threadIdx.x == 0) out[0] = (float)(sd[0] / (double)NPIX);
}

extern "C" void kernel_launch(void* const* d_in, const int* in_sizes, int n_in,
                              void* d_out, int out_size, void* d_ws, size_t ws_size,
                              hipStream_t stream) {
    const float* A = (const float*)d_in[0];
    const float* B = (const float*)d_in[1];
    float* out = (float*)d_out;

    double* partial = (double*)d_ws;   // 1024 * 8 = 8 KiB

    cl_fused_kernel<<<NROW, 256, 0, stream>>>(A, B, partial);
    cl_final_kernel<<<1, 256, 0, stream>>>(partial, out);
}